// Round 3
// baseline (113.664 us; speedup 1.0000x reference)
//
#include <hip/hip_runtime.h>
#include <cstdint>
#include <cmath>

// ---------------------------------------------------------------------------
// MHKPattLayer fused kernel for MI355X (gfx950) — round 3
//   QBLK=64, 1024 threads (16 waves), 1 block/CU.
//   3-pass bf16-split QK^T (swapped, lane-local rows), f32 l2norm+GELU+mask,
//   bf16 PV with all 16 waves (16x16x32 MFMA).
//   L2 traffic halved vs round 2 (K+V streamed once per 64 q-rows).
// B=4, T=2048, C=1024, H=8, N=1024, Dk=Dv=128
// ---------------------------------------------------------------------------

typedef __bf16 bf16x8 __attribute__((ext_vector_type(8)));
typedef float  f32x16 __attribute__((ext_vector_type(16)));
typedef float  f32x4  __attribute__((ext_vector_type(4)));
typedef unsigned short u16x8 __attribute__((ext_vector_type(8)));

__device__ __forceinline__ unsigned short bfbits(__bf16 b) {
  return __builtin_bit_cast(unsigned short, b);
}

// exact GELU via A&S 7.1.26 erf (|eps| <= 1.5e-7), branchless
__device__ __forceinline__ float gelu_exact(float v) {
  const float s = v * 0.70710678118654752f;
  const float a = fabsf(s);
  const float t = __builtin_amdgcn_rcpf(fmaf(0.3275911f, a, 1.0f));
  float p = fmaf(1.061405429f, t, -1.453152027f);
  p = fmaf(p, t, 1.421413741f);
  p = fmaf(p, t, -0.284496736f);
  p = fmaf(p, t, 0.254829592f);
  p *= t;
  const float e = __expf(-a * a);
  float er = fmaf(-p, e, 1.0f);
  er = copysignf(er, s);
  return 0.5f * v * (1.0f + er);
}

// ---------------- prep kernels ----------------
// K (fp32 [8][1024][128]) -> hi/lo bf16 fragment-packed: [h][kc=16][n=1024][e=8]
// element = key[h][n][kc*8+e]
__global__ void prep_k(const float* __restrict__ key,
                       unsigned short* __restrict__ kh,
                       unsigned short* __restrict__ kl) {
  const int tid = blockIdx.x * 256 + threadIdx.x;   // 0..131071
  const int h   = tid >> 14;
  const int kc  = (tid >> 10) & 15;
  const int n   = tid & 1023;
  const float* src = key + ((size_t)(h << 10) + n) * 128 + kc * 8;
  const float4 f0 = *(const float4*)src;
  const float4 f1 = *(const float4*)(src + 4);
  const float fv[8] = {f0.x, f0.y, f0.z, f0.w, f1.x, f1.y, f1.z, f1.w};
  u16x8 hv, lv;
#pragma unroll
  for (int e = 0; e < 8; ++e) {
    const __bf16 hb = (__bf16)fv[e];
    hv[e] = bfbits(hb);
    lv[e] = bfbits((__bf16)(fv[e] - (float)hb));
  }
  const size_t o = ((size_t)(h * 16 + kc) * 1024 + n) * 8;
  *(u16x8*)(kh + o) = hv;
  *(u16x8*)(kl + o) = lv;
}

// V (fp32 [8][1024][128]) -> bf16 fragment-packed: [h][s2=128][v=128][e=8]
// element = val[h][s2*8+e][v]
__global__ void prep_v(const float* __restrict__ val,
                       unsigned short* __restrict__ vp) {
  const int tid = blockIdx.x * 256 + threadIdx.x;   // 0..131071
  const int h   = tid >> 14;
  const int s2  = (tid >> 7) & 127;
  const int v   = tid & 127;
  const float* src = val + ((size_t)(h << 10) + s2 * 8) * 128 + v;
  u16x8 ov;
#pragma unroll
  for (int e = 0; e < 8; ++e) ov[e] = bfbits((__bf16)src[(size_t)e * 128]);
  *(u16x8*)(vp + ((size_t)(h * 128 + s2) * 128 + v) * 8) = ov;
}

// ---------------- fused kernel ----------------
// grid 1024 (h = bid&7 -> one head per XCD), 1024 threads (16 waves)
// LDS map (bytes):
//   [0, 131072)      S bf16, frag-major granules: g = ng*64 + (q ^ (ng&7)),
//                    ng = n/8 (0..127), q = 0..63; 16B per granule.
//                    Aliased during phases 0-1: Q-hi [0,16384) granules
//                    g = kc*64 + (r ^ (kc>>1 & 7)); Q-lo at +16384.
//   [131072, 135168) red1 (16 waves x 64 q, f32)
//   [135168, 139264) red2
#define RED1   131072
#define RED2   135168
#define SMEMSZ 139264

__global__ __launch_bounds__(1024, 4) void fused_mhk(
    const float* __restrict__ x,
    const unsigned short* __restrict__ k_hi,
    const unsigned short* __restrict__ k_lo,
    const unsigned short* __restrict__ v_pk,
    float* __restrict__ out)
{
  extern __shared__ char smem[];
  const int tid  = threadIdx.x;
  const int wave = tid >> 6;      // 0..15
  const int lane = tid & 63;
  const int l31  = lane & 31;
  const int hi   = lane >> 5;

  const int bid = blockIdx.x;
  const int h   = bid & 7;        // head fixed per XCD slot
  const int g8  = bid >> 3;       // 0..127
  const int b   = g8 & 3;
  const int tt  = g8 >> 2;        // 0..31
  const int t0  = tt * 64;

  // ---- Phase 0: load Q tile [64][128] fp32, split hi/lo bf16 -> LDS (swizzled)
  {
    const float* xq = x + ((size_t)(b * 2048 + t0)) * 1024 + h * 128;
    const int r  = tid >> 4;      // 0..63 (q row)
    const int kc = tid & 15;      // 8-elem k chunk
    const float* sp = xq + (size_t)r * 1024 + kc * 8;
    const float4 f0 = *(const float4*)sp;
    const float4 f1 = *(const float4*)(sp + 4);
    const float fv[8] = {f0.x, f0.y, f0.z, f0.w, f1.x, f1.y, f1.z, f1.w};
    bf16x8 hv; u16x8 lv;
#pragma unroll
    for (int e = 0; e < 8; ++e) {
      const __bf16 hb = (__bf16)fv[e];
      hv[e] = hb;
      lv[e] = bfbits((__bf16)(fv[e] - (float)hb));
    }
    const int g = kc * 64 + (r ^ ((kc >> 1) & 7));
    *(bf16x8*)(smem + g * 16) = hv;
    *(u16x8*)(smem + 16384 + g * 16) = lv;
  }
  __syncthreads();

  // ---- Phase 1: swapped QK^T. acc[t][qt]: lane holds q = qt*32+l31,
  //      n = wave*64 + t*32 + crow(r,hi), crow = (r&3)+8*(r>>2)+4*hi
  f32x16 acc[2][2];
#pragma unroll
  for (int t = 0; t < 2; ++t)
#pragma unroll
    for (int qt = 0; qt < 2; ++qt)
#pragma unroll
      for (int i = 0; i < 16; ++i) acc[t][qt][i] = 0.f;

  {
    const unsigned short* kph = k_hi + (size_t)h * 131072;
    const unsigned short* kpl = k_lo + (size_t)h * 131072;
    // shorts offset: (2s+hi)*8192 + (wave*64 + t*32 + l31)*8
    const size_t kb = (size_t)hi * 8192 + (size_t)(wave * 64 + l31) * 8;
    const int hi64 = hi * 64;
#pragma unroll
    for (int s = 0; s < 8; ++s) {
      bf16x8 bqh[2], bql[2];
#pragma unroll
      for (int qt = 0; qt < 2; ++qt) {
        const int gx = (2 * s) * 64 + hi64 + ((qt * 32 + l31) ^ s);
        bqh[qt] = *(const bf16x8*)(smem + gx * 16);
        bql[qt] = *(const bf16x8*)(smem + 16384 + gx * 16);
      }
      const unsigned short* kah = kph + kb + s * 16384;
      const unsigned short* kal = kpl + kb + s * 16384;
#pragma unroll
      for (int t = 0; t < 2; ++t) {
        const bf16x8 ah = *(const bf16x8*)(kah + t * 256);
        const bf16x8 al = *(const bf16x8*)(kal + t * 256);
        acc[t][0] = __builtin_amdgcn_mfma_f32_32x32x16_bf16(ah, bqh[0], acc[t][0], 0, 0, 0);
        acc[t][1] = __builtin_amdgcn_mfma_f32_32x32x16_bf16(ah, bqh[1], acc[t][1], 0, 0, 0);
        acc[t][0] = __builtin_amdgcn_mfma_f32_32x32x16_bf16(ah, bql[0], acc[t][0], 0, 0, 0);
        acc[t][1] = __builtin_amdgcn_mfma_f32_32x32x16_bf16(ah, bql[1], acc[t][1], 0, 0, 0);
        acc[t][0] = __builtin_amdgcn_mfma_f32_32x32x16_bf16(al, bqh[0], acc[t][0], 0, 0, 0);
        acc[t][1] = __builtin_amdgcn_mfma_f32_32x32x16_bf16(al, bqh[1], acc[t][1], 0, 0, 0);
      }
    }
  }

  // ---- Phase 2: l2-norm -> scale -> GELU -> mean (per q-row, lane-local n-slice)
  float* red1 = (float*)(smem + RED1);
  float* red2 = (float*)(smem + RED2);

  float ss0 = 0.f, ss1 = 0.f;
#pragma unroll
  for (int t = 0; t < 2; ++t)
#pragma unroll
    for (int i = 0; i < 16; ++i) {
      ss0 += acc[t][0][i] * acc[t][0][i];
      ss1 += acc[t][1][i] * acc[t][1][i];
    }
  ss0 += __shfl_xor(ss0, 32);
  ss1 += __shfl_xor(ss1, 32);
  if (lane < 32) {
    red1[wave * 64 + lane]      = ss0;
    red1[wave * 64 + 32 + lane] = ss1;
  }
  __syncthreads();
  float sum0 = 0.f, sum1 = 0.f;
#pragma unroll
  for (int w = 0; w < 16; ++w) {
    sum0 += red1[w * 64 + l31];
    sum1 += red1[w * 64 + 32 + l31];
  }
  const float scale0 = 32.0f / fmaxf(sqrtf(sum0), 1e-8f);
  const float scale1 = 32.0f / fmaxf(sqrtf(sum1), 1e-8f);

  float gs0 = 0.f, gs1 = 0.f;
#pragma unroll
  for (int t = 0; t < 2; ++t)
#pragma unroll
    for (int i = 0; i < 16; ++i) {
      const float g0 = gelu_exact(acc[t][0][i] * scale0);
      acc[t][0][i] = g0; gs0 += g0;
      const float g1 = gelu_exact(acc[t][1][i] * scale1);
      acc[t][1][i] = g1; gs1 += g1;
    }
  gs0 += __shfl_xor(gs0, 32);
  gs1 += __shfl_xor(gs1, 32);
  if (lane < 32) {
    red2[wave * 64 + lane]      = gs0;
    red2[wave * 64 + 32 + lane] = gs1;
  }
  __syncthreads();
  float mean0 = 0.f, mean1 = 0.f;
#pragma unroll
  for (int w = 0; w < 16; ++w) {
    mean0 += red2[w * 64 + l31];
    mean1 += red2[w * 64 + 32 + l31];
  }
  mean0 *= (1.0f / 1024.0f);
  mean1 *= (1.0f / 1024.0f);

  // ---- Phase 3: mask (strict >) + bf16 pack -> S frag-major granules in LDS
  // n = wave*64 + t*32 + 8*gi + (u) + 4*hi, u=0..3 -> granule ng = wave*8+t*4+gi,
  // in-granule byte = hi*8 + u*2.  byte = (ng*64 + (q ^ (ng&7)))*16 + hi*8
#pragma unroll
  for (int t = 0; t < 2; ++t) {
#pragma unroll
    for (int qt = 0; qt < 2; ++qt) {
      const float mn = qt ? mean1 : mean0;
      const int q = qt * 32 + l31;
#pragma unroll
      for (int gi = 0; gi < 4; ++gi) {
        float g0 = acc[t][qt][4 * gi + 0]; g0 = (g0 > mn) ? g0 : 0.f;
        float g1 = acc[t][qt][4 * gi + 1]; g1 = (g1 > mn) ? g1 : 0.f;
        float g2 = acc[t][qt][4 * gi + 2]; g2 = (g2 > mn) ? g2 : 0.f;
        float g3 = acc[t][qt][4 * gi + 3]; g3 = (g3 > mn) ? g3 : 0.f;
        uint2 pk;
        pk.x = (unsigned)bfbits((__bf16)g0) | ((unsigned)bfbits((__bf16)g1) << 16);
        pk.y = (unsigned)bfbits((__bf16)g2) | ((unsigned)bfbits((__bf16)g3) << 16);
        const int ng = wave * 8 + t * 4 + gi;
        const int swz = (t * 4 + gi) & 7;               // = ng & 7
        *(uint2*)(smem + (ng * 64 + (q ^ swz)) * 16 + hi * 8) = pk;
      }
    }
  }
  __syncthreads();

  // ---- Phase 4: PV, all 16 waves. wave -> (qt2 = w>>3, vt = w&7),
  //      out rect 32q x 16v over full n (32 k-steps of 32).
  const int l15 = lane & 15;
  const int l4  = lane >> 4;        // 0..3
  const int qt2 = wave >> 3;
  const int vt  = wave & 7;

  f32x4 o0, o1;
#pragma unroll
  for (int i = 0; i < 4; ++i) { o0[i] = 0.f; o1[i] = 0.f; }

  // B-frag: lane holds V[n = ks*32 + l4*8 + e][v = vt*16 + l15]
  const unsigned short* vb = v_pk + (size_t)h * 131072 + (size_t)l4 * 1024 +
                             (size_t)(vt * 16 + l15) * 8;
  const int qa = qt2 * 32 + l15;    // sub-tile 0 row; sub-tile 1 = qa+16
#pragma unroll 8
  for (int ks = 0; ks < 32; ++ks) {
    const int swz = (ks & 1) * 4 + l4;                  // = (ks*4+l4)&7
    const int ngb = (ks * 4 + l4) * 64;
    const bf16x8 a0 = *(const bf16x8*)(smem + (ngb + (qa ^ swz)) * 16);
    const bf16x8 a1 = *(const bf16x8*)(smem + (ngb + ((qa + 16) ^ swz)) * 16);
    const bf16x8 bb = *(const bf16x8*)(vb + (size_t)ks * 4096);
    o0 = __builtin_amdgcn_mfma_f32_16x16x32_bf16(a0, bb, o0, 0, 0, 0);
    o1 = __builtin_amdgcn_mfma_f32_16x16x32_bf16(a1, bb, o1, 0, 0, 0);
  }

  // C/D 16x16: col = l15 (v), row = l4*4 + j (q within 16-tile)
  float* op = out + ((size_t)(b * 2048 + t0 + qt2 * 32 + l4 * 4)) * 1024 +
              h * 128 + vt * 16 + l15;
#pragma unroll
  for (int j = 0; j < 4; ++j) {
    op[(size_t)j * 1024]        = o0[j];
    op[(size_t)(16 + j) * 1024] = o1[j];
  }
}

// ---------------- launch ----------------

extern "C" void kernel_launch(void* const* d_in, const int* in_sizes, int n_in,
                              void* d_out, int out_size, void* d_ws, size_t ws_size,
                              hipStream_t stream) {
  const float* x   = (const float*)d_in[0];  // [4][2048][1024]
  const float* key = (const float*)d_in[1];  // [8][1024][128]
  const float* val = (const float*)d_in[2];  // [8][1024][128]
  float* out = (float*)d_out;                // [4][2048][1024]

  if (ws_size < (size_t)6 * 1024 * 1024) return;  // need 6 MB scratch

  unsigned short* k_hi = (unsigned short*)d_ws;   // 1M bf16 (2 MB)
  unsigned short* k_lo = k_hi + 1048576;          // 1M bf16
  unsigned short* v_pk = k_lo + 1048576;          // 1M bf16 (frag-packed V)

  prep_k<<<dim3(512), dim3(256), 0, stream>>>(key, k_hi, k_lo);
  prep_v<<<dim3(512), dim3(256), 0, stream>>>(val, v_pk);
  fused_mhk<<<dim3(1024), dim3(1024), SMEMSZ, stream>>>(x, k_hi, k_lo, v_pk, out);
}

// Round 4
// 113.591 us; speedup vs baseline: 1.0006x; 1.0006x over previous
//
#include <hip/hip_runtime.h>
#include <cstdint>
#include <cmath>

// ---------------------------------------------------------------------------
// MHKPattLayer fused kernel for MI355X (gfx950) — round 4
//   QBLK=64, 1024 threads (16 waves), 1 block/CU.
//   3-pass bf16-split QK^T (swapped, lane-local rows), f32 l2norm+GELU+mask,
//   bf16 PV on 8 waves with 32x32 tiles (non-redundant -> half the LDS reads).
//   GELU via A&S 7.1.28 (1 TRANS op). Prep fused into one kernel.
// B=4, T=2048, C=1024, H=8, N=1024, Dk=Dv=128
// ---------------------------------------------------------------------------

typedef __bf16 bf16x8 __attribute__((ext_vector_type(8)));
typedef float  f32x16 __attribute__((ext_vector_type(16)));
typedef unsigned short u16x8 __attribute__((ext_vector_type(8)));

__device__ __forceinline__ unsigned short bfbits(__bf16 b) {
  return __builtin_bit_cast(unsigned short, b);
}

// exact GELU, scale pre-folded: g = gelu(raw*scale), c707 = scale/sqrt(2),
// chalf = scale*0.5.  erf via A&S 7.1.28: 1-(1+a1 x..a6 x^6)^-16, |eps|<=3e-7.
__device__ __forceinline__ float gelu_s(float raw, float c707, float chalf) {
  const float s = raw * c707;
  const float a = fabsf(s);
  float u = fmaf(a, 4.30638e-5f, 2.765672e-4f);
  u = fmaf(u, a, 1.520143e-4f);
  u = fmaf(u, a, 9.2705272e-3f);
  u = fmaf(u, a, 4.22820123e-2f);
  u = fmaf(u, a, 7.05230784e-2f);
  u = fmaf(u, a, 1.0f);
  const float r  = __builtin_amdgcn_rcpf(u);   // u >= 1 always
  const float r2 = r * r;
  const float r4 = r2 * r2;
  const float r8 = r4 * r4;
  const float r16 = r8 * r8;
  const float er = copysignf(1.0f - r16, s);
  const float hf = raw * chalf;
  return fmaf(hf, er, hf);
}

// ---------------- fused prep kernel ----------------
// first 131072 threads: K -> hi/lo bf16 frag-packed [h][kc=16][n=1024][e=8]
// next  131072 threads: V -> bf16 frag-packed      [h][s2=128][v=128][e=8]
__global__ void prep_kv(const float* __restrict__ key,
                        const float* __restrict__ val,
                        unsigned short* __restrict__ kh,
                        unsigned short* __restrict__ kl,
                        unsigned short* __restrict__ vp) {
  const int gid = blockIdx.x * 256 + threadIdx.x;   // 0..262143
  if (gid < 131072) {
    const int h  = gid >> 14;
    const int kc = (gid >> 10) & 15;
    const int n  = gid & 1023;
    const float* src = key + ((size_t)(h << 10) + n) * 128 + kc * 8;
    const float4 f0 = *(const float4*)src;
    const float4 f1 = *(const float4*)(src + 4);
    const float fv[8] = {f0.x, f0.y, f0.z, f0.w, f1.x, f1.y, f1.z, f1.w};
    u16x8 hv, lv;
#pragma unroll
    for (int e = 0; e < 8; ++e) {
      const __bf16 hb = (__bf16)fv[e];
      hv[e] = bfbits(hb);
      lv[e] = bfbits((__bf16)(fv[e] - (float)hb));
    }
    const size_t o = ((size_t)(h * 16 + kc) * 1024 + n) * 8;
    *(u16x8*)(kh + o) = hv;
    *(u16x8*)(kl + o) = lv;
  } else {
    const int tid = gid - 131072;
    const int h   = tid >> 14;
    const int s2  = (tid >> 7) & 127;
    const int v   = tid & 127;
    const float* src = val + ((size_t)(h << 10) + s2 * 8) * 128 + v;
    u16x8 ov;
#pragma unroll
    for (int e = 0; e < 8; ++e) ov[e] = bfbits((__bf16)src[(size_t)e * 128]);
    *(u16x8*)(vp + ((size_t)(h * 128 + s2) * 128 + v) * 8) = ov;
  }
}

// ---------------- fused kernel ----------------
// grid 1024 (h = bid&7 -> one head per XCD), 1024 threads (16 waves)
// LDS map (bytes):
//   [0, 131072)      S bf16, frag-major granules: slot = ng*64 + (q ^ (ng&7)),
//                    ng = n/8 (0..127), q = 0..63; 16B per granule.
//                    Aliased during phases 0-1: Q-hi [0,16384) granules
//                    g = kc*64 + (r ^ ((kc>>1)&7)); Q-lo at +16384.
//   [131072, 135168) red1 (16 waves x 64 q, f32)
//   [135168, 139264) red2
#define RED1   131072
#define RED2   135168
#define SMEMSZ 139264

__global__ __launch_bounds__(1024, 4) void fused_mhk(
    const float* __restrict__ x,
    const unsigned short* __restrict__ k_hi,
    const unsigned short* __restrict__ k_lo,
    const unsigned short* __restrict__ v_pk,
    float* __restrict__ out)
{
  extern __shared__ char smem[];
  const int tid  = threadIdx.x;
  const int wave = tid >> 6;      // 0..15
  const int lane = tid & 63;
  const int l31  = lane & 31;
  const int hi   = lane >> 5;

  const int bid = blockIdx.x;
  const int h   = bid & 7;        // head fixed per XCD slot
  const int g8  = bid >> 3;       // 0..127
  const int b   = g8 & 3;
  const int tt  = g8 >> 2;        // 0..31
  const int t0  = tt * 64;

  // ---- Phase 0: load Q tile [64][128] fp32, split hi/lo bf16 -> LDS (swizzled)
  {
    const float* xq = x + ((size_t)(b * 2048 + t0)) * 1024 + h * 128;
    const int r  = tid >> 4;      // 0..63 (q row)
    const int kc = tid & 15;      // 8-elem k chunk
    const float* sp = xq + (size_t)r * 1024 + kc * 8;
    const float4 f0 = *(const float4*)sp;
    const float4 f1 = *(const float4*)(sp + 4);
    const float fv[8] = {f0.x, f0.y, f0.z, f0.w, f1.x, f1.y, f1.z, f1.w};
    bf16x8 hv; u16x8 lv;
#pragma unroll
    for (int e = 0; e < 8; ++e) {
      const __bf16 hb = (__bf16)fv[e];
      hv[e] = hb;
      lv[e] = bfbits((__bf16)(fv[e] - (float)hb));
    }
    const int g = kc * 64 + (r ^ ((kc >> 1) & 7));
    *(bf16x8*)(smem + g * 16) = hv;
    *(u16x8*)(smem + 16384 + g * 16) = lv;
  }
  __syncthreads();

  // ---- Phase 1: swapped QK^T. acc[t][qt]: lane holds q = qt*32+l31,
  //      n = wave*64 + t*32 + crow(r,hi), crow = (r&3)+8*(r>>2)+4*hi
  f32x16 acc[2][2];
#pragma unroll
  for (int t = 0; t < 2; ++t)
#pragma unroll
    for (int qt = 0; qt < 2; ++qt)
#pragma unroll
      for (int i = 0; i < 16; ++i) acc[t][qt][i] = 0.f;

  {
    const unsigned short* kph = k_hi + (size_t)h * 131072;
    const unsigned short* kpl = k_lo + (size_t)h * 131072;
    const size_t kb = (size_t)hi * 8192 + (size_t)(wave * 64 + l31) * 8;
    const int hi64 = hi * 64;
#pragma unroll
    for (int s = 0; s < 8; ++s) {
      bf16x8 bqh[2], bql[2];
#pragma unroll
      for (int qt = 0; qt < 2; ++qt) {
        const int gx = (2 * s) * 64 + hi64 + ((qt * 32 + l31) ^ s);
        bqh[qt] = *(const bf16x8*)(smem + gx * 16);
        bql[qt] = *(const bf16x8*)(smem + 16384 + gx * 16);
      }
      const unsigned short* kah = kph + kb + s * 16384;
      const unsigned short* kal = kpl + kb + s * 16384;
#pragma unroll
      for (int t = 0; t < 2; ++t) {
        const bf16x8 ah = *(const bf16x8*)(kah + t * 256);
        const bf16x8 al = *(const bf16x8*)(kal + t * 256);
        acc[t][0] = __builtin_amdgcn_mfma_f32_32x32x16_bf16(ah, bqh[0], acc[t][0], 0, 0, 0);
        acc[t][1] = __builtin_amdgcn_mfma_f32_32x32x16_bf16(ah, bqh[1], acc[t][1], 0, 0, 0);
        acc[t][0] = __builtin_amdgcn_mfma_f32_32x32x16_bf16(ah, bql[0], acc[t][0], 0, 0, 0);
        acc[t][1] = __builtin_amdgcn_mfma_f32_32x32x16_bf16(ah, bql[1], acc[t][1], 0, 0, 0);
        acc[t][0] = __builtin_amdgcn_mfma_f32_32x32x16_bf16(al, bqh[0], acc[t][0], 0, 0, 0);
        acc[t][1] = __builtin_amdgcn_mfma_f32_32x32x16_bf16(al, bqh[1], acc[t][1], 0, 0, 0);
      }
    }
  }

  // ---- Phase 2: l2-norm -> scale -> GELU -> mean (per q-row, lane-local n-slice)
  float* red1 = (float*)(smem + RED1);
  float* red2 = (float*)(smem + RED2);

  float ss0 = 0.f, ss1 = 0.f;
#pragma unroll
  for (int t = 0; t < 2; ++t)
#pragma unroll
    for (int i = 0; i < 16; ++i) {
      ss0 += acc[t][0][i] * acc[t][0][i];
      ss1 += acc[t][1][i] * acc[t][1][i];
    }
  ss0 += __shfl_xor(ss0, 32);
  ss1 += __shfl_xor(ss1, 32);
  red1[wave * 64 + lane] = hi ? ss1 : ss0;    // full-wave write, no exec mask
  __syncthreads();
  float sum0 = 0.f, sum1 = 0.f;
#pragma unroll
  for (int w = 0; w < 16; ++w) {
    sum0 += red1[w * 64 + l31];
    sum1 += red1[w * 64 + 32 + l31];
  }
  const float scale0 = 32.0f / fmaxf(sqrtf(sum0), 1e-8f);
  const float scale1 = 32.0f / fmaxf(sqrtf(sum1), 1e-8f);
  const float c707_0 = scale0 * 0.70710678118654752f;
  const float c707_1 = scale1 * 0.70710678118654752f;
  const float chalf0 = scale0 * 0.5f;
  const float chalf1 = scale1 * 0.5f;

  float gs0 = 0.f, gs1 = 0.f;
#pragma unroll
  for (int t = 0; t < 2; ++t)
#pragma unroll
    for (int i = 0; i < 16; ++i) {
      const float g0 = gelu_s(acc[t][0][i], c707_0, chalf0);
      acc[t][0][i] = g0; gs0 += g0;
      const float g1 = gelu_s(acc[t][1][i], c707_1, chalf1);
      acc[t][1][i] = g1; gs1 += g1;
    }
  gs0 += __shfl_xor(gs0, 32);
  gs1 += __shfl_xor(gs1, 32);
  red2[wave * 64 + lane] = hi ? gs1 : gs0;
  __syncthreads();
  float mean0 = 0.f, mean1 = 0.f;
#pragma unroll
  for (int w = 0; w < 16; ++w) {
    mean0 += red2[w * 64 + l31];
    mean1 += red2[w * 64 + 32 + l31];
  }
  mean0 *= (1.0f / 1024.0f);
  mean1 *= (1.0f / 1024.0f);

  // ---- Phase 3: mask (strict >) + bf16 pack -> S frag-major granules in LDS
  // n = wave*64 + t*32 + 8*gi + u + 4*hi (u=0..3) -> granule ng = wave*8+t*4+gi,
  // byte = (ng*64 + (q ^ (ng&7)))*16 + hi*8
#pragma unroll
  for (int t = 0; t < 2; ++t) {
#pragma unroll
    for (int qt = 0; qt < 2; ++qt) {
      const float mn = qt ? mean1 : mean0;
      const int q = qt * 32 + l31;
#pragma unroll
      for (int gi = 0; gi < 4; ++gi) {
        float g0 = acc[t][qt][4 * gi + 0]; g0 = (g0 > mn) ? g0 : 0.f;
        float g1 = acc[t][qt][4 * gi + 1]; g1 = (g1 > mn) ? g1 : 0.f;
        float g2 = acc[t][qt][4 * gi + 2]; g2 = (g2 > mn) ? g2 : 0.f;
        float g3 = acc[t][qt][4 * gi + 3]; g3 = (g3 > mn) ? g3 : 0.f;
        uint2 pk;
        pk.x = (unsigned)bfbits((__bf16)g0) | ((unsigned)bfbits((__bf16)g1) << 16);
        pk.y = (unsigned)bfbits((__bf16)g2) | ((unsigned)bfbits((__bf16)g3) << 16);
        const int ng = wave * 8 + t * 4 + gi;
        const int swz = (t * 4 + gi) & 7;               // = ng & 7
        *(uint2*)(smem + (ng * 64 + (q ^ swz)) * 16 + hi * 8) = pk;
      }
    }
  }
  __syncthreads();

  // ---- Phase 4: PV on 8 waves, 32x32 tiles (no redundancy).
  //      wave -> (qt2 = w>>2, vt = w&3); full n sweep, 64 k-steps of 16.
  if (wave >= 8) return;
  const int qt2 = wave >> 2;
  const int vt  = wave & 3;
  const int q   = qt2 * 32 + l31;

  f32x16 o;
#pragma unroll
  for (int i = 0; i < 16; ++i) o[i] = 0.f;

  // A-frag (32x32x16): lane (l31=row q, hi=k-half): S[q][n=ks*16+hi*8+e]
  //   -> granule ng = 2*ks + hi at slot ng*64 + (q ^ (ng&7))
  // B-frag: lane (l31=col v, hi=k-half): V[n][v=vt*32+l31] from frag-packed v_pk
  const unsigned short* vb = v_pk + (size_t)h * 131072 + (size_t)hi * 1024 +
                             (size_t)(vt * 32 + l31) * 8;
#pragma unroll 8
  for (int ks = 0; ks < 64; ++ks) {
    const int ng = 2 * ks + hi;
    const bf16x8 aa = *(const bf16x8*)(smem + (ng * 64 + (q ^ (ng & 7))) * 16);
    const bf16x8 bb = *(const bf16x8*)(vb + (size_t)ks * 2048);
    o = __builtin_amdgcn_mfma_f32_32x32x16_bf16(aa, bb, o, 0, 0, 0);
  }

  // C/D 32x32: col = l31 (v), row = crow(r,hi) (q within 32-tile)
  float* op = out + ((size_t)(b * 2048 + t0 + qt2 * 32)) * 1024 +
              h * 128 + vt * 32 + l31;
#pragma unroll
  for (int r = 0; r < 16; ++r) {
    const int qr = (r & 3) + 8 * (r >> 2) + 4 * hi;
    op[(size_t)qr * 1024] = o[r];
  }
}

// ---------------- launch ----------------

extern "C" void kernel_launch(void* const* d_in, const int* in_sizes, int n_in,
                              void* d_out, int out_size, void* d_ws, size_t ws_size,
                              hipStream_t stream) {
  const float* x   = (const float*)d_in[0];  // [4][2048][1024]
  const float* key = (const float*)d_in[1];  // [8][1024][128]
  const float* val = (const float*)d_in[2];  // [8][1024][128]
  float* out = (float*)d_out;                // [4][2048][1024]

  if (ws_size < (size_t)6 * 1024 * 1024) return;  // need 6 MB scratch

  unsigned short* k_hi = (unsigned short*)d_ws;   // 1M bf16 (2 MB)
  unsigned short* k_lo = k_hi + 1048576;          // 1M bf16
  unsigned short* v_pk = k_lo + 1048576;          // 1M bf16 (frag-packed V)

  prep_kv<<<dim3(1024), dim3(256), 0, stream>>>(key, val, k_hi, k_lo, v_pk);
  fused_mhk<<<dim3(1024), dim3(1024), SMEMSZ, stream>>>(x, k_hi, k_lo, v_pk, out);
}